// Round 9
// baseline (518.672 us; speedup 1.0000x reference)
//
#include <hip/hip_runtime.h>
#include <hip/hip_bf16.h>

typedef __bf16 bf16_t;
typedef unsigned short u16;
typedef short short8 __attribute__((ext_vector_type(8)));
typedef float f32x4 __attribute__((ext_vector_type(4)));

#define BSHIFT 9            // 512 dst-rows per bucket
#define CAP 8192            // fixed slots per bucket (expected 6144 +- 78; 26 sigma)
#define TILE 16384          // edges per partition tile (1024 thr x 16)

__device__ inline short f2bs(float v) {
    bf16_t h = (bf16_t)v;
    return __builtin_bit_cast(short, h);
}
__device__ inline float uif(unsigned u) { return __builtin_bit_cast(float, u); }

// ---------------- prep: plane convert + weights (incl. W_out-composites) + cursors ----
// wh mats (transposed [n*64+k], bf16):
//   0..5  Wn[l*3+e]            (layer-1 uses 0..2; 3..5 unused now but cheap)
//   6,7   WrB[l]=Wr[l,0]
//   8,9   WrA[l]=Wr[l,1]+Wr[l,2]
//   10    W_out (unused by fused path; kept for layout stability)
//   11    Wn[1,0]@W_out   12  Wr[1,0]@W_out
//   13    Wn[1,1]@W_out   14  Wn[1,2]@W_out   15  (Wr[1,1]+Wr[1,2])@W_out
// biasC f32[4][64]: 0 = b[0,0]; 1 = b[0,1]+b[0,2];
//                   2 = b[1,0]@W_out + b_out; 3 = (b[1,1]+b[1,2])@W_out + b_out
__global__ __launch_bounds__(256) void prep_convert(
    const float* __restrict__ xA, const float* __restrict__ xB,
    const float* __restrict__ Wn, const float* __restrict__ Wr,
    const float* __restrict__ Wout, const float* __restrict__ b,
    const float* __restrict__ b_out,
    u16* __restrict__ plane0, u16* __restrict__ wh,
    int* __restrict__ gcursor, float* __restrict__ biasC,
    int NA, int NB, int K) {
    int nA4 = NA * 16, nB4 = NB * 16;
    int bA = (nA4 + 255) / 256, bB = (nB4 + 255) / 256;
    int bi = blockIdx.x;
    int tid = threadIdx.x;
    if (bi < bA + bB) {
        const float* in = (bi < bA) ? xA : xB;
        u16* out = (bi < bA) ? plane0 : plane0 + (size_t)NA * 64;
        int i = (bi < bA ? bi : bi - bA) * 256 + tid;
        int n4 = (bi < bA) ? nA4 : nB4;
        if (i >= n4) return;
        float4 v = ((const float4*)in)[i];
        u16 o[4];
        o[0] = (u16)f2bs(v.x); o[1] = (u16)f2bs(v.y);
        o[2] = (u16)f2bs(v.z); o[3] = (u16)f2bs(v.w);
        *(uint2*)(out + (size_t)i * 4) = *(uint2*)o;
        return;
    }
    if (bi < bA + bB + 11) {
        int mat = bi - bA - bB;      // 0..10
        u16* dstp = wh + (size_t)mat * 4096;
        for (int i = tid; i < 4096; i += 256) {
            int k = i >> 6, n = i & 63;
            float v;
            if (mat < 6) v = Wn[(size_t)mat * 4096 + i];
            else if (mat < 8) v = Wr[(size_t)((mat - 6) * 3 + 0) * 4096 + i];
            else if (mat < 10) v = Wr[(size_t)((mat - 8) * 3 + 1) * 4096 + i]
                                 + Wr[(size_t)((mat - 8) * 3 + 2) * 4096 + i];
            else v = Wout[i];
            dstp[n * 64 + k] = (u16)f2bs(v);
        }
        return;
    }
    if (bi < bA + bB + 11 + 5) {
        // composite mats: W' = Wsrc @ W_out (f32 accumulate, bf16 store, transposed)
        int c = bi - bA - bB - 11;   // 0..4
        const float* Wsrc;
        const float* Wsrc2 = nullptr;
        if (c == 0) Wsrc = Wn + (size_t)3 * 4096;        // Wn[1,0]
        else if (c == 1) Wsrc = Wr + (size_t)3 * 4096;   // Wr[1,0]
        else if (c == 2) Wsrc = Wn + (size_t)4 * 4096;   // Wn[1,1]
        else if (c == 3) Wsrc = Wn + (size_t)5 * 4096;   // Wn[1,2]
        else { Wsrc = Wr + (size_t)4 * 4096; Wsrc2 = Wr + (size_t)5 * 4096; }
        u16* dstp = wh + (size_t)(11 + c) * 4096;
        for (int i = tid; i < 4096; i += 256) {
            int k = i >> 6, n = i & 63;
            float s = 0.f;
            for (int j = 0; j < 64; j++) {
                float w = Wsrc[k * 64 + j];
                if (Wsrc2) w += Wsrc2[k * 64 + j];
                s += w * Wout[j * 64 + n];
            }
            dstp[n * 64 + k] = (u16)f2bs(s);
        }
        return;
    }
    // last block: cursor init + bias precompute
    for (int i = tid; i < K; i += 256) gcursor[i] = i * CAP;
    if (tid < 64) {
        int n = tid;
        float s0 = b_out[n], s1 = b_out[n];
        for (int j = 0; j < 64; j++) {
            float wo = Wout[j * 64 + n];
            s0 += b[3 * 64 + j] * wo;                       // b[1,0]
            s1 += (b[4 * 64 + j] + b[5 * 64 + j]) * wo;     // b[1,1]+b[1,2]
        }
        biasC[0 * 64 + n] = b[0 * 64 + n];                  // b[0,0]
        biasC[1 * 64 + n] = b[1 * 64 + n] + b[2 * 64 + n];  // b[0,1]+b[0,2]
        biasC[2 * 64 + n] = s0;
        biasC[3 * 64 + n] = s1;
    }
}

// pairs entry: packed = ((g & 511) << 17) | src   (src < 2^17, bucket = g >> 9)
// bucket b's region is [b*CAP, b*CAP + cnt_b). Scan-free: per tile, rank via LDS
// hist atomic; reserve per-bucket global range; write directly.
__global__ __launch_bounds__(1024) void partition_kernel(
    const int* __restrict__ s0, const int* __restrict__ d0,
    const int* __restrict__ s1, const int* __restrict__ d1,
    const int* __restrict__ s2, const int* __restrict__ d2,
    int* __restrict__ gcursor, int* __restrict__ pairs,
    int NB, int NA, int E, int total) {
    __shared__ int hist[1024];
    __shared__ int gbase[1024];
    int tid = threadIdx.x;
    for (int tile = blockIdx.x * TILE; tile < total; tile += gridDim.x * TILE) {
        hist[tid] = 0;
        __syncthreads();
        int mybkt[16], mypk[16], myrank[16];
#pragma unroll
        for (int j = 0; j < 16; j++) {
            int idx = tile + j * 1024 + tid;
            int g = -1, s = 0;
            if (idx < total) {
                if (idx < E) { s = s0[idx]; g = d0[idx]; }
                else if (idx < 2 * E) { s = s1[idx - E]; g = NB + d1[idx - E]; }
                else { s = s2[idx - 2 * E]; g = NB + NA + d2[idx - 2 * E]; }
            }
            if (g >= 0) {
                mybkt[j] = g >> BSHIFT;
                mypk[j] = ((g & ((1 << BSHIFT) - 1)) << 17) | s;
                myrank[j] = atomicAdd(&hist[mybkt[j]], 1);
            } else mybkt[j] = -1;
        }
        __syncthreads();
        {
            int c = hist[tid];
            if (c) gbase[tid] = atomicAdd(&gcursor[tid], c);
        }
        __syncthreads();
#pragma unroll
        for (int j = 0; j < 16; j++) {
            if (mybkt[j] >= 0)
                pairs[gbase[mybkt[j]] + myrank[j]] = mypk[j];
        }
        __syncthreads();   // hist/gbase stable before next iteration's zeroing
    }
}

// bucket b: order pairs into colidx segments; emit per-row [off_s, off_e).
__global__ __launch_bounds__(512) void bucket_fill(const int* __restrict__ pairs,
                                                   const int* __restrict__ gcursor,
                                                   int* __restrict__ off_s,
                                                   int* __restrict__ off_e,
                                                   int* __restrict__ colidx, int M) {
    int b = blockIdx.x;
    int gb = b << BSHIFT;
    __shared__ int cnt[512], cur[512], wsum[8];
    int tid = threadIdx.x;
    int lane = tid & 63, w = tid >> 6;
    int p0 = b * CAP, p1 = gcursor[b];
    cnt[tid] = 0;
    __syncthreads();
    for (int e = p0 + tid; e < p1; e += 512)
        atomicAdd(&cnt[(unsigned)pairs[e] >> 17], 1);
    __syncthreads();
    int v = cnt[tid];
    int x = v;
#pragma unroll
    for (int off = 1; off < 64; off <<= 1) {
        int n = __shfl_up(x, off);
        if (lane >= off) x += n;
    }
    if (lane == 63) wsum[w] = x;
    __syncthreads();
    if (tid == 0) {
        int s = 0;
#pragma unroll
        for (int i = 0; i < 8; i++) { int t = wsum[i]; wsum[i] = s; s += t; }
    }
    __syncthreads();
    int excl = x - v + wsum[w];          // exclusive prefix of cnt over 512 rows
    cur[tid] = excl;
    int g = gb + tid;
    if (g < M) { off_s[g] = p0 + excl; off_e[g] = p0 + excl + v; }
    __syncthreads();
    for (int e = p0 + tid; e < p1; e += 512) {
        int p = pairs[e];
        int pos = atomicAdd(&cur[(unsigned)p >> 17], 1);
        colidx[p0 + pos] = p & 0x1FFFF;
    }
}

// ---------------- gather-mean: one row per 8-lane octet, dwordx4, 4-deep pipeline ----
// Bound by random-row L2-miss BW (59 us / 48% HBM, stable across rounds).
__device__ __forceinline__ void acc8(uint4 u, f32x4& a0, f32x4& a1) {
    a0[0] += uif(u.x << 16); a0[1] += uif(u.x & 0xFFFF0000u);
    a0[2] += uif(u.y << 16); a0[3] += uif(u.y & 0xFFFF0000u);
    a1[0] += uif(u.z << 16); a1[1] += uif(u.z & 0xFFFF0000u);
    a1[2] += uif(u.w << 16); a1[3] += uif(u.w & 0xFFFF0000u);
}

__global__ __launch_bounds__(256) void gather_all(const u16* __restrict__ plane,
                                                  const int* __restrict__ colidx,
                                                  const int* __restrict__ off_s,
                                                  const int* __restrict__ off_e,
                                                  u16* __restrict__ meanB,
                                                  u16* __restrict__ meanA1,
                                                  u16* __restrict__ meanA2,
                                                  int NB, int NA) {
    int wid = (blockIdx.x * 256 + threadIdx.x) >> 6;   // wave id
    int lane = threadIdx.x & 63;
    int oct = lane >> 3, fl = lane & 7;
    int M = NB + 2 * NA;
    int grow = wid * 8 + oct;
    if (grow >= M) return;

    const char* tab;
    u16* outp;
    int orow;
    if (grow < NB) { tab = (const char*)plane; outp = meanB; orow = grow; }
    else if (grow < NB + NA) { tab = (const char*)(plane + (size_t)NA * 64); outp = meanA1; orow = grow - NB; }
    else { tab = (const char*)plane; outp = meanA2; orow = grow - NB - NA; }

    int s0 = off_s[grow], s1 = off_e[grow];
    unsigned fo = (unsigned)(fl << 4);                 // byte offset within row
    f32x4 a0 = {0.f, 0.f, 0.f, 0.f}, a1 = {0.f, 0.f, 0.f, 0.f};

    int e = s0;
    if (e + 3 < s1) {
        int c0 = colidx[e], c1 = colidx[e + 1];
        int c2 = colidx[e + 2], c3 = colidx[e + 3];
        while (e + 7 < s1) {
            uint4 u0 = *(const uint4*)(tab + (((unsigned)c0 << 7) | fo));
            uint4 u1 = *(const uint4*)(tab + (((unsigned)c1 << 7) | fo));
            uint4 u2 = *(const uint4*)(tab + (((unsigned)c2 << 7) | fo));
            uint4 u3 = *(const uint4*)(tab + (((unsigned)c3 << 7) | fo));
            c0 = colidx[e + 4]; c1 = colidx[e + 5];    // prefetch next quad
            c2 = colidx[e + 6]; c3 = colidx[e + 7];
            acc8(u0, a0, a1); acc8(u1, a0, a1);
            acc8(u2, a0, a1); acc8(u3, a0, a1);
            e += 4;
        }
        {   // drain the pipelined quad
            uint4 u0 = *(const uint4*)(tab + (((unsigned)c0 << 7) | fo));
            uint4 u1 = *(const uint4*)(tab + (((unsigned)c1 << 7) | fo));
            uint4 u2 = *(const uint4*)(tab + (((unsigned)c2 << 7) | fo));
            uint4 u3 = *(const uint4*)(tab + (((unsigned)c3 << 7) | fo));
            acc8(u0, a0, a1); acc8(u1, a0, a1);
            acc8(u2, a0, a1); acc8(u3, a0, a1);
            e += 4;
        }
    }
    for (; e < s1; ++e) {                              // up to 3 leftovers
        int c = colidx[e];
        uint4 u = *(const uint4*)(tab + (((unsigned)c << 7) | fo));
        acc8(u, a0, a1);
    }

    float inv = 1.0f / fmaxf((float)(s1 - s0), 1.0f);
    u16 o[8];
#pragma unroll
    for (int i = 0; i < 4; i++) o[i] = (u16)f2bs(a0[i] * inv);
#pragma unroll
    for (int i = 0; i < 4; i++) o[4 + i] = (u16)f2bs(a1[i] * inv);
    *(uint4*)(outp + (size_t)orow * 64 + fl * 8) = *(uint4*)o;
}

// ---------------- linear body (bf16 in, MFMA, bf16 or f32+relu out) ----------------
// A[m=lane&15][k=(lane>>4)*8+j], B[k][n=lane&15] (pre-transposed),
// C/D row=(lane>>4)*4+reg, col=lane&15. Single pre-summed f32 bias[64].
template <int NM, int RELU, int OUTF32>
__device__ __forceinline__ void lin_body(
    const u16* __restrict__ m0, const u16* __restrict__ m1,
    const u16* __restrict__ x,
    const u16* __restrict__ Wm0t, const u16* __restrict__ Wm1t,
    const u16* __restrict__ Wxt,
    const float* __restrict__ bias64,
    void* __restrict__ outv, int nrows, int blk) {
    const int lane = threadIdx.x & 63;
    const int wave = threadIdx.x >> 6;
    const int row0 = blk * 64 + wave * 16;
    if (row0 >= nrows) return;
    const int r = lane & 15;
    const int q = lane >> 4;

    f32x4 acc[4];
#pragma unroll
    for (int t = 0; t < 4; t++) {
        float bv = bias64[t * 16 + r];
        acc[t][0] = bv; acc[t][1] = bv; acc[t][2] = bv; acc[t][3] = bv;
    }

    const int arow = row0 + r;
    const bool avalid = arow < nrows;
    short8 zf;
#pragma unroll
    for (int j = 0; j < 8; j++) zf[j] = 0;

#pragma unroll
    for (int ks = 0; ks < 2; ks++) {
        short8 af = avalid ? *(const short8*)(m0 + (size_t)arow * 64 + ks * 32 + q * 8) : zf;
        short8 xf = avalid ? *(const short8*)(x + (size_t)arow * 64 + ks * 32 + q * 8) : zf;
        short8 bf_;
        if (NM >= 2) bf_ = avalid ? *(const short8*)(m1 + (size_t)arow * 64 + ks * 32 + q * 8) : zf;
#pragma unroll
        for (int t = 0; t < 4; t++) {
            size_t widx = (size_t)(t * 16 + r) * 64 + ks * 32 + q * 8;
            acc[t] = __builtin_amdgcn_mfma_f32_16x16x32_bf16(af, *(const short8*)(Wm0t + widx), acc[t], 0, 0, 0);
            if (NM >= 2)
                acc[t] = __builtin_amdgcn_mfma_f32_16x16x32_bf16(bf_, *(const short8*)(Wm1t + widx), acc[t], 0, 0, 0);
            acc[t] = __builtin_amdgcn_mfma_f32_16x16x32_bf16(xf, *(const short8*)(Wxt + widx), acc[t], 0, 0, 0);
        }
    }

#pragma unroll
    for (int t = 0; t < 4; t++) {
#pragma unroll
        for (int rr = 0; rr < 4; rr++) {
            int row = row0 + q * 4 + rr;
            if (row < nrows) {
                float v = acc[t][rr];
                if (RELU) v = fmaxf(v, 0.0f);
                if (OUTF32)
                    __builtin_nontemporal_store(v, (float*)outv + (size_t)row * 64 + t * 16 + r);
                else
                    ((u16*)outv)[(size_t)row * 64 + t * 16 + r] = (u16)f2bs(v);
            }
        }
    }
}

__global__ __launch_bounds__(256) void layer1_kernel(
    const u16* __restrict__ plane_in, u16* __restrict__ plane_out,
    const u16* __restrict__ meanB, const u16* __restrict__ meanA1,
    const u16* __restrict__ meanA2, const u16* __restrict__ wh,
    const float* __restrict__ biasC, int NA, int NB, int blocksB) {
    if ((int)blockIdx.x < blocksB) {
        lin_body<1, 0, 0>(meanB, nullptr, plane_in + (size_t)NA * 64,
                          wh + (size_t)0 * 4096, nullptr, wh + (size_t)6 * 4096,
                          biasC + 0 * 64,
                          plane_out + (size_t)NA * 64, NB, blockIdx.x);
    } else {
        lin_body<2, 0, 0>(meanA1, meanA2, plane_in,
                          wh + (size_t)1 * 4096, wh + (size_t)2 * 4096, wh + (size_t)8 * 4096,
                          biasC + 1 * 64,
                          plane_out, NA, blockIdx.x - blocksB);
    }
}

// layer-2 + head via W_out-composited weights: out = relu(m@W' + x@Wx' + b'),
// single MFMA pass, no LDS, no barrier. (y is never materialized.)
__global__ __launch_bounds__(256) void layer2_head_kernel(
    const u16* __restrict__ plane_in,
    const u16* __restrict__ meanB, const u16* __restrict__ meanA1,
    const u16* __restrict__ meanA2, const u16* __restrict__ wh,
    const float* __restrict__ biasC,
    float* __restrict__ out, int NA, int NB, int blocksB) {
    if ((int)blockIdx.x < blocksB) {
        // new_B rows -> out rows [NA, NA+NB)
        lin_body<1, 1, 1>(meanB, nullptr, plane_in + (size_t)NA * 64,
                          wh + (size_t)11 * 4096, nullptr, wh + (size_t)12 * 4096,
                          biasC + 2 * 64,
                          out + (size_t)NA * 64, NB, blockIdx.x);
    } else {
        // new_A rows -> out rows [0, NA)
        lin_body<2, 1, 1>(meanA1, meanA2, plane_in,
                          wh + (size_t)13 * 4096, wh + (size_t)14 * 4096, wh + (size_t)15 * 4096,
                          biasC + 3 * 64,
                          out, NA, blockIdx.x - blocksB);
    }
}

// ---------------- launch ----------------
extern "C" void kernel_launch(void* const* d_in, const int* in_sizes, int n_in,
                              void* d_out, int out_size, void* d_ws, size_t ws_size,
                              hipStream_t stream) {
    const float* xA_in = (const float*)d_in[0];
    const float* xB_in = (const float*)d_in[1];
    const float* Wn = (const float*)d_in[2];
    const float* Wr = (const float*)d_in[3];
    const float* b = (const float*)d_in[4];
    const float* W_out = (const float*)d_in[5];
    const float* b_out = (const float*)d_in[6];
    const int* src0 = (const int*)d_in[7];
    const int* dst0 = (const int*)d_in[8];
    const int* src1 = (const int*)d_in[9];
    const int* dst1 = (const int*)d_in[10];
    const int* src2 = (const int*)d_in[11];
    const int* dst2 = (const int*)d_in[12];

    const int NA = in_sizes[0] / 64;
    const int NB = in_sizes[1] / 64;
    const int E = in_sizes[7];
    const int M = NB + NA + NA;
    const int total = 3 * E;
    const int K = (M + (1 << BSHIFT) - 1) >> BSHIFT;   // 586 for 300k dst rows

    // ---- workspace ----
    const size_t PL = (size_t)(NA + NB) * 64;
    u16* plane[2];
    plane[0] = (u16*)d_ws;
    plane[1] = plane[0] + PL;
    u16* wh     = plane[1] + PL;                 // 16*4096
    u16* meanB  = wh + 16 * 4096;
    u16* meanA1 = meanB + (size_t)NB * 64;
    u16* meanA2 = meanA1 + (size_t)NA * 64;
    int* gcursor= (int*)(meanA2 + (size_t)NA * 64); // K (alloc 1024)
    float* biasC= (float*)(gcursor + 1024);      // 4*64 f32
    int* off_s  = (int*)(biasC + 256);           // M
    int* off_e  = off_s + M;                     // M
    int* colidx = off_e + M;                     // K*CAP (bucket-padded)
    int* pairs  = (int*)meanB;                   // K*CAP, aliases means (dead until gathers)

    // ---- prep (convert + weights + composites + cursor/bias init) ----
    int bA = (NA * 16 + 255) / 256, bB = (NB * 16 + 255) / 256;
    prep_convert<<<bA + bB + 11 + 5 + 1, 256, 0, stream>>>(
        xA_in, xB_in, Wn, Wr, W_out, b, b_out,
        plane[0], wh, gcursor, biasC, NA, NB, K);

    // ---- CSR build: fixed-capacity buckets, scan-free partition ----
    int ntiles = (total + TILE - 1) / TILE;
    partition_kernel<<<ntiles, 1024, 0, stream>>>(src0, dst0, src1, dst1, src2, dst2,
                                                  gcursor, pairs, NB, NA, E, total);
    bucket_fill<<<K, 512, 0, stream>>>(pairs, gcursor, off_s, off_e, colidx, M);

    // ---- layer 1: gather + MFMA layer (bf16 plane out) ----
    const int blocksB = (NB + 63) / 64;
    const int blocksA = (NA + 63) / 64;
    gather_all<<<(M + 31) / 32, 256, 0, stream>>>(plane[0], colidx, off_s, off_e,
                                                  meanB, meanA1, meanA2, NB, NA);
    layer1_kernel<<<blocksB + blocksA, 256, 0, stream>>>(
        plane[0], plane[1], meanB, meanA1, meanA2, wh, biasC, NA, NB, blocksB);

    // ---- layer 2 + head fused via composite weights (f32 out) ----
    gather_all<<<(M + 31) / 32, 256, 0, stream>>>(plane[1], colidx, off_s, off_e,
                                                  meanB, meanA1, meanA2, NB, NA);
    layer2_head_kernel<<<blocksB + blocksA, 256, 0, stream>>>(
        plane[1], meanB, meanA1, meanA2, wh, biasC, (float*)d_out, NA, NB, blocksB);
}

// Round 10
// 410.977 us; speedup vs baseline: 1.2620x; 1.2620x over previous
//
#include <hip/hip_runtime.h>
#include <hip/hip_bf16.h>

typedef __bf16 bf16_t;
typedef unsigned short u16;
typedef short short8 __attribute__((ext_vector_type(8)));
typedef float f32x4 __attribute__((ext_vector_type(4)));

#define BSHIFT 9            // 512 dst-rows per bucket
#define CAP 8192            // fixed slots per bucket (expected 6144 +- 78; 26 sigma)
#define TILE 16384          // edges per partition tile (1024 thr x 16)

__device__ inline short f2bs(float v) {
    bf16_t h = (bf16_t)v;
    return __builtin_bit_cast(short, h);
}
__device__ inline float uif(unsigned u) { return __builtin_bit_cast(float, u); }

// ---------------- prep: plane convert + weights (incl. W_out-composites) + cursors ----
// wh mats (transposed [n*64+k], bf16):
//   0..5  Wn[l*3+e]            (layer-1 uses 0..2)
//   6,7   WrB[l]=Wr[l,0]
//   8,9   WrA[l]=Wr[l,1]+Wr[l,2]
//   10    W_out (unused by fused path; kept for layout stability)
//   11    Wn[1,0]@W_out   12  Wr[1,0]@W_out
//   13    Wn[1,1]@W_out   14  Wn[1,2]@W_out   15  (Wr[1,1]+Wr[1,2])@W_out
// biasC f32[4][64]: 0 = b[0,0]; 1 = b[0,1]+b[0,2];
//                   2 = b[1,0]@W_out + b_out; 3 = (b[1,1]+b[1,2])@W_out + b_out
// Composite blocks stage BOTH mats in LDS first (coalesced) -- the round-9
// scalar-global-load version was a 130 us latency chain (5 CUs, 0 TLP).
__global__ __launch_bounds__(256) void prep_convert(
    const float* __restrict__ xA, const float* __restrict__ xB,
    const float* __restrict__ Wn, const float* __restrict__ Wr,
    const float* __restrict__ Wout, const float* __restrict__ b,
    const float* __restrict__ b_out,
    u16* __restrict__ plane0, u16* __restrict__ wh,
    int* __restrict__ gcursor, float* __restrict__ biasC,
    int NA, int NB, int K) {
    int nA4 = NA * 16, nB4 = NB * 16;
    int bA = (nA4 + 255) / 256, bB = (nB4 + 255) / 256;
    int bi = blockIdx.x;
    int tid = threadIdx.x;
    if (bi < bA + bB) {
        const float* in = (bi < bA) ? xA : xB;
        u16* out = (bi < bA) ? plane0 : plane0 + (size_t)NA * 64;
        int i = (bi < bA ? bi : bi - bA) * 256 + tid;
        int n4 = (bi < bA) ? nA4 : nB4;
        if (i >= n4) return;
        float4 v = ((const float4*)in)[i];
        u16 o[4];
        o[0] = (u16)f2bs(v.x); o[1] = (u16)f2bs(v.y);
        o[2] = (u16)f2bs(v.z); o[3] = (u16)f2bs(v.w);
        *(uint2*)(out + (size_t)i * 4) = *(uint2*)o;
        return;
    }
    if (bi < bA + bB + 11) {
        int mat = bi - bA - bB;      // 0..10
        u16* dstp = wh + (size_t)mat * 4096;
        for (int i = tid; i < 4096; i += 256) {
            int k = i >> 6, n = i & 63;
            float v;
            if (mat < 6) v = Wn[(size_t)mat * 4096 + i];
            else if (mat < 8) v = Wr[(size_t)((mat - 6) * 3 + 0) * 4096 + i];
            else if (mat < 10) v = Wr[(size_t)((mat - 8) * 3 + 1) * 4096 + i]
                                 + Wr[(size_t)((mat - 8) * 3 + 2) * 4096 + i];
            else v = Wout[i];
            dstp[n * 64 + k] = (u16)f2bs(v);
        }
        return;
    }
    if (bi < bA + bB + 11 + 5) {
        // composite mats: W' = Wsrc @ W_out (LDS-staged, f32 acc, bf16 store, transposed)
        int c = bi - bA - bB - 11;   // 0..4
        const float* Wsrc;
        const float* Wsrc2 = nullptr;
        if (c == 0) Wsrc = Wn + (size_t)3 * 4096;        // Wn[1,0]
        else if (c == 1) Wsrc = Wr + (size_t)3 * 4096;   // Wr[1,0]
        else if (c == 2) Wsrc = Wn + (size_t)4 * 4096;   // Wn[1,1]
        else if (c == 3) Wsrc = Wn + (size_t)5 * 4096;   // Wn[1,2]
        else { Wsrc = Wr + (size_t)4 * 4096; Wsrc2 = Wr + (size_t)5 * 4096; }
        __shared__ float Ws[64 * 64];
        __shared__ float Wo[64 * 64];
        for (int i = tid; i < 4096; i += 256) {
            float w = Wsrc[i];
            if (Wsrc2) w += Wsrc2[i];
            Ws[i] = w;
            Wo[i] = Wout[i];
        }
        __syncthreads();
        u16* dstp = wh + (size_t)(11 + c) * 4096;
        for (int it = 0; it < 16; ++it) {
            int i = it * 256 + tid;
            int k = i >> 6, n = i & 63;    // k wave-uniform -> Ws broadcast reads
            float s0 = 0.f, s1 = 0.f, s2 = 0.f, s3 = 0.f;
#pragma unroll
            for (int j = 0; j < 64; j += 4) {
                s0 += Ws[k * 64 + j]     * Wo[j * 64 + n];
                s1 += Ws[k * 64 + j + 1] * Wo[(j + 1) * 64 + n];
                s2 += Ws[k * 64 + j + 2] * Wo[(j + 2) * 64 + n];
                s3 += Ws[k * 64 + j + 3] * Wo[(j + 3) * 64 + n];
            }
            dstp[n * 64 + k] = (u16)f2bs((s0 + s1) + (s2 + s3));
        }
        return;
    }
    // last block: cursor init + bias precompute
    for (int i = tid; i < K; i += 256) gcursor[i] = i * CAP;
    if (tid < 64) {
        int n = tid;
        float s0 = b_out[n], s1 = b_out[n];
        for (int j = 0; j < 64; j++) {
            float wo = Wout[j * 64 + n];
            s0 += b[3 * 64 + j] * wo;                       // b[1,0]
            s1 += (b[4 * 64 + j] + b[5 * 64 + j]) * wo;     // b[1,1]+b[1,2]
        }
        biasC[0 * 64 + n] = b[0 * 64 + n];                  // b[0,0]
        biasC[1 * 64 + n] = b[1 * 64 + n] + b[2 * 64 + n];  // b[0,1]+b[0,2]
        biasC[2 * 64 + n] = s0;
        biasC[3 * 64 + n] = s1;
    }
}

// pairs entry: packed = ((g & 511) << 17) | src   (src < 2^17, bucket = g >> 9)
// bucket b's region is [b*CAP, b*CAP + cnt_b). Scan-free: per tile, rank via LDS
// hist atomic; reserve per-bucket global range; write directly.
__global__ __launch_bounds__(1024) void partition_kernel(
    const int* __restrict__ s0, const int* __restrict__ d0,
    const int* __restrict__ s1, const int* __restrict__ d1,
    const int* __restrict__ s2, const int* __restrict__ d2,
    int* __restrict__ gcursor, int* __restrict__ pairs,
    int NB, int NA, int E, int total) {
    __shared__ int hist[1024];
    __shared__ int gbase[1024];
    int tid = threadIdx.x;
    for (int tile = blockIdx.x * TILE; tile < total; tile += gridDim.x * TILE) {
        hist[tid] = 0;
        __syncthreads();
        int mybkt[16], mypk[16], myrank[16];
#pragma unroll
        for (int j = 0; j < 16; j++) {
            int idx = tile + j * 1024 + tid;
            int g = -1, s = 0;
            if (idx < total) {
                if (idx < E) { s = s0[idx]; g = d0[idx]; }
                else if (idx < 2 * E) { s = s1[idx - E]; g = NB + d1[idx - E]; }
                else { s = s2[idx - 2 * E]; g = NB + NA + d2[idx - 2 * E]; }
            }
            if (g >= 0) {
                mybkt[j] = g >> BSHIFT;
                mypk[j] = ((g & ((1 << BSHIFT) - 1)) << 17) | s;
                myrank[j] = atomicAdd(&hist[mybkt[j]], 1);
            } else mybkt[j] = -1;
        }
        __syncthreads();
        {
            int c = hist[tid];
            if (c) gbase[tid] = atomicAdd(&gcursor[tid], c);
        }
        __syncthreads();
#pragma unroll
        for (int j = 0; j < 16; j++) {
            if (mybkt[j] >= 0)
                pairs[gbase[mybkt[j]] + myrank[j]] = mypk[j];
        }
        __syncthreads();   // hist/gbase stable before next iteration's zeroing
    }
}

// bucket b: order pairs into colidx segments; emit per-row [off_s, off_e).
__global__ __launch_bounds__(512) void bucket_fill(const int* __restrict__ pairs,
                                                   const int* __restrict__ gcursor,
                                                   int* __restrict__ off_s,
                                                   int* __restrict__ off_e,
                                                   int* __restrict__ colidx, int M) {
    int b = blockIdx.x;
    int gb = b << BSHIFT;
    __shared__ int cnt[512], cur[512], wsum[8];
    int tid = threadIdx.x;
    int lane = tid & 63, w = tid >> 6;
    int p0 = b * CAP, p1 = gcursor[b];
    cnt[tid] = 0;
    __syncthreads();
    for (int e = p0 + tid; e < p1; e += 512)
        atomicAdd(&cnt[(unsigned)pairs[e] >> 17], 1);
    __syncthreads();
    int v = cnt[tid];
    int x = v;
#pragma unroll
    for (int off = 1; off < 64; off <<= 1) {
        int n = __shfl_up(x, off);
        if (lane >= off) x += n;
    }
    if (lane == 63) wsum[w] = x;
    __syncthreads();
    if (tid == 0) {
        int s = 0;
#pragma unroll
        for (int i = 0; i < 8; i++) { int t = wsum[i]; wsum[i] = s; s += t; }
    }
    __syncthreads();
    int excl = x - v + wsum[w];          // exclusive prefix of cnt over 512 rows
    cur[tid] = excl;
    int g = gb + tid;
    if (g < M) { off_s[g] = p0 + excl; off_e[g] = p0 + excl + v; }
    __syncthreads();
    for (int e = p0 + tid; e < p1; e += 512) {
        int p = pairs[e];
        int pos = atomicAdd(&cur[(unsigned)p >> 17], 1);
        colidx[p0 + pos] = p & 0x1FFFF;
    }
}

// ---------------- gather-mean: one row per 8-lane octet, dwordx4, 4-deep pipeline ----
// Bound by random-row L2-miss BW (59 us / 48% HBM, stable across rounds).
__device__ __forceinline__ void acc8(uint4 u, f32x4& a0, f32x4& a1) {
    a0[0] += uif(u.x << 16); a0[1] += uif(u.x & 0xFFFF0000u);
    a0[2] += uif(u.y << 16); a0[3] += uif(u.y & 0xFFFF0000u);
    a1[0] += uif(u.z << 16); a1[1] += uif(u.z & 0xFFFF0000u);
    a1[2] += uif(u.w << 16); a1[3] += uif(u.w & 0xFFFF0000u);
}

__global__ __launch_bounds__(256) void gather_all(const u16* __restrict__ plane,
                                                  const int* __restrict__ colidx,
                                                  const int* __restrict__ off_s,
                                                  const int* __restrict__ off_e,
                                                  u16* __restrict__ meanB,
                                                  u16* __restrict__ meanA1,
                                                  u16* __restrict__ meanA2,
                                                  int NB, int NA) {
    int wid = (blockIdx.x * 256 + threadIdx.x) >> 6;   // wave id
    int lane = threadIdx.x & 63;
    int oct = lane >> 3, fl = lane & 7;
    int M = NB + 2 * NA;
    int grow = wid * 8 + oct;
    if (grow >= M) return;

    const char* tab;
    u16* outp;
    int orow;
    if (grow < NB) { tab = (const char*)plane; outp = meanB; orow = grow; }
    else if (grow < NB + NA) { tab = (const char*)(plane + (size_t)NA * 64); outp = meanA1; orow = grow - NB; }
    else { tab = (const char*)plane; outp = meanA2; orow = grow - NB - NA; }

    int s0 = off_s[grow], s1 = off_e[grow];
    unsigned fo = (unsigned)(fl << 4);                 // byte offset within row
    f32x4 a0 = {0.f, 0.f, 0.f, 0.f}, a1 = {0.f, 0.f, 0.f, 0.f};

    int e = s0;
    if (e + 3 < s1) {
        int c0 = colidx[e], c1 = colidx[e + 1];
        int c2 = colidx[e + 2], c3 = colidx[e + 3];
        while (e + 7 < s1) {
            uint4 u0 = *(const uint4*)(tab + (((unsigned)c0 << 7) | fo));
            uint4 u1 = *(const uint4*)(tab + (((unsigned)c1 << 7) | fo));
            uint4 u2 = *(const uint4*)(tab + (((unsigned)c2 << 7) | fo));
            uint4 u3 = *(const uint4*)(tab + (((unsigned)c3 << 7) | fo));
            c0 = colidx[e + 4]; c1 = colidx[e + 5];    // prefetch next quad
            c2 = colidx[e + 6]; c3 = colidx[e + 7];
            acc8(u0, a0, a1); acc8(u1, a0, a1);
            acc8(u2, a0, a1); acc8(u3, a0, a1);
            e += 4;
        }
        {   // drain the pipelined quad
            uint4 u0 = *(const uint4*)(tab + (((unsigned)c0 << 7) | fo));
            uint4 u1 = *(const uint4*)(tab + (((unsigned)c1 << 7) | fo));
            uint4 u2 = *(const uint4*)(tab + (((unsigned)c2 << 7) | fo));
            uint4 u3 = *(const uint4*)(tab + (((unsigned)c3 << 7) | fo));
            acc8(u0, a0, a1); acc8(u1, a0, a1);
            acc8(u2, a0, a1); acc8(u3, a0, a1);
            e += 4;
        }
    }
    for (; e < s1; ++e) {                              // up to 3 leftovers
        int c = colidx[e];
        uint4 u = *(const uint4*)(tab + (((unsigned)c << 7) | fo));
        acc8(u, a0, a1);
    }

    float inv = 1.0f / fmaxf((float)(s1 - s0), 1.0f);
    u16 o[8];
#pragma unroll
    for (int i = 0; i < 4; i++) o[i] = (u16)f2bs(a0[i] * inv);
#pragma unroll
    for (int i = 0; i < 4; i++) o[4 + i] = (u16)f2bs(a1[i] * inv);
    *(uint4*)(outp + (size_t)orow * 64 + fl * 8) = *(uint4*)o;
}

// ---------------- linear body (bf16 in, MFMA, bf16 or f32+relu out) ----------------
// A[m=lane&15][k=(lane>>4)*8+j], B[k][n=lane&15] (pre-transposed),
// C/D row=(lane>>4)*4+reg, col=lane&15. Single pre-summed f32 bias[64].
template <int NM, int RELU, int OUTF32>
__device__ __forceinline__ void lin_body(
    const u16* __restrict__ m0, const u16* __restrict__ m1,
    const u16* __restrict__ x,
    const u16* __restrict__ Wm0t, const u16* __restrict__ Wm1t,
    const u16* __restrict__ Wxt,
    const float* __restrict__ bias64,
    void* __restrict__ outv, int nrows, int blk) {
    const int lane = threadIdx.x & 63;
    const int wave = threadIdx.x >> 6;
    const int row0 = blk * 64 + wave * 16;
    if (row0 >= nrows) return;
    const int r = lane & 15;
    const int q = lane >> 4;

    f32x4 acc[4];
#pragma unroll
    for (int t = 0; t < 4; t++) {
        float bv = bias64[t * 16 + r];
        acc[t][0] = bv; acc[t][1] = bv; acc[t][2] = bv; acc[t][3] = bv;
    }

    const int arow = row0 + r;
    const bool avalid = arow < nrows;
    short8 zf;
#pragma unroll
    for (int j = 0; j < 8; j++) zf[j] = 0;

#pragma unroll
    for (int ks = 0; ks < 2; ks++) {
        short8 af = avalid ? *(const short8*)(m0 + (size_t)arow * 64 + ks * 32 + q * 8) : zf;
        short8 xf = avalid ? *(const short8*)(x + (size_t)arow * 64 + ks * 32 + q * 8) : zf;
        short8 bf_;
        if (NM >= 2) bf_ = avalid ? *(const short8*)(m1 + (size_t)arow * 64 + ks * 32 + q * 8) : zf;
#pragma unroll
        for (int t = 0; t < 4; t++) {
            size_t widx = (size_t)(t * 16 + r) * 64 + ks * 32 + q * 8;
            acc[t] = __builtin_amdgcn_mfma_f32_16x16x32_bf16(af, *(const short8*)(Wm0t + widx), acc[t], 0, 0, 0);
            if (NM >= 2)
                acc[t] = __builtin_amdgcn_mfma_f32_16x16x32_bf16(bf_, *(const short8*)(Wm1t + widx), acc[t], 0, 0, 0);
            acc[t] = __builtin_amdgcn_mfma_f32_16x16x32_bf16(xf, *(const short8*)(Wxt + widx), acc[t], 0, 0, 0);
        }
    }

#pragma unroll
    for (int t = 0; t < 4; t++) {
#pragma unroll
        for (int rr = 0; rr < 4; rr++) {
            int row = row0 + q * 4 + rr;
            if (row < nrows) {
                float v = acc[t][rr];
                if (RELU) v = fmaxf(v, 0.0f);
                if (OUTF32)
                    __builtin_nontemporal_store(v, (float*)outv + (size_t)row * 64 + t * 16 + r);
                else
                    ((u16*)outv)[(size_t)row * 64 + t * 16 + r] = (u16)f2bs(v);
            }
        }
    }
}

__global__ __launch_bounds__(256) void layer1_kernel(
    const u16* __restrict__ plane_in, u16* __restrict__ plane_out,
    const u16* __restrict__ meanB, const u16* __restrict__ meanA1,
    const u16* __restrict__ meanA2, const u16* __restrict__ wh,
    const float* __restrict__ biasC, int NA, int NB, int blocksB) {
    if ((int)blockIdx.x < blocksB) {
        lin_body<1, 0, 0>(meanB, nullptr, plane_in + (size_t)NA * 64,
                          wh + (size_t)0 * 4096, nullptr, wh + (size_t)6 * 4096,
                          biasC + 0 * 64,
                          plane_out + (size_t)NA * 64, NB, blockIdx.x);
    } else {
        lin_body<2, 0, 0>(meanA1, meanA2, plane_in,
                          wh + (size_t)1 * 4096, wh + (size_t)2 * 4096, wh + (size_t)8 * 4096,
                          biasC + 1 * 64,
                          plane_out, NA, blockIdx.x - blocksB);
    }
}

// layer-2 + head via W_out-composited weights: out = relu(m@W' + x@Wx' + b'),
// single MFMA pass, no LDS, no barrier. (y is never materialized.)
__global__ __launch_bounds__(256) void layer2_head_kernel(
    const u16* __restrict__ plane_in,
    const u16* __restrict__ meanB, const u16* __restrict__ meanA1,
    const u16* __restrict__ meanA2, const u16* __restrict__ wh,
    const float* __restrict__ biasC,
    float* __restrict__ out, int NA, int NB, int blocksB) {
    if ((int)blockIdx.x < blocksB) {
        // new_B rows -> out rows [NA, NA+NB)
        lin_body<1, 1, 1>(meanB, nullptr, plane_in + (size_t)NA * 64,
                          wh + (size_t)11 * 4096, nullptr, wh + (size_t)12 * 4096,
                          biasC + 2 * 64,
                          out + (size_t)NA * 64, NB, blockIdx.x);
    } else {
        // new_A rows -> out rows [0, NA)
        lin_body<2, 1, 1>(meanA1, meanA2, plane_in,
                          wh + (size_t)13 * 4096, wh + (size_t)14 * 4096, wh + (size_t)15 * 4096,
                          biasC + 3 * 64,
                          out, NA, blockIdx.x - blocksB);
    }
}

// ---------------- launch ----------------
extern "C" void kernel_launch(void* const* d_in, const int* in_sizes, int n_in,
                              void* d_out, int out_size, void* d_ws, size_t ws_size,
                              hipStream_t stream) {
    const float* xA_in = (const float*)d_in[0];
    const float* xB_in = (const float*)d_in[1];
    const float* Wn = (const float*)d_in[2];
    const float* Wr = (const float*)d_in[3];
    const float* b = (const float*)d_in[4];
    const float* W_out = (const float*)d_in[5];
    const float* b_out = (const float*)d_in[6];
    const int* src0 = (const int*)d_in[7];
    const int* dst0 = (const int*)d_in[8];
    const int* src1 = (const int*)d_in[9];
    const int* dst1 = (const int*)d_in[10];
    const int* src2 = (const int*)d_in[11];
    const int* dst2 = (const int*)d_in[12];

    const int NA = in_sizes[0] / 64;
    const int NB = in_sizes[1] / 64;
    const int E = in_sizes[7];
    const int M = NB + NA + NA;
    const int total = 3 * E;
    const int K = (M + (1 << BSHIFT) - 1) >> BSHIFT;   // 586 for 300k dst rows

    // ---- workspace ----
    const size_t PL = (size_t)(NA + NB) * 64;
    u16* plane[2];
    plane[0] = (u16*)d_ws;
    plane[1] = plane[0] + PL;
    u16* wh     = plane[1] + PL;                 // 16*4096
    u16* meanB  = wh + 16 * 4096;
    u16* meanA1 = meanB + (size_t)NB * 64;
    u16* meanA2 = meanA1 + (size_t)NA * 64;
    int* gcursor= (int*)(meanA2 + (size_t)NA * 64); // K (alloc 1024)
    float* biasC= (float*)(gcursor + 1024);      // 4*64 f32
    int* off_s  = (int*)(biasC + 256);           // M
    int* off_e  = off_s + M;                     // M
    int* colidx = off_e + M;                     // K*CAP (bucket-padded)
    int* pairs  = (int*)meanB;                   // K*CAP, aliases means (dead until gathers)

    // ---- prep (convert + weights + composites + cursor/bias init) ----
    int bA = (NA * 16 + 255) / 256, bB = (NB * 16 + 255) / 256;
    prep_convert<<<bA + bB + 11 + 5 + 1, 256, 0, stream>>>(
        xA_in, xB_in, Wn, Wr, W_out, b, b_out,
        plane[0], wh, gcursor, biasC, NA, NB, K);

    // ---- CSR build: fixed-capacity buckets, scan-free partition ----
    int ntiles = (total + TILE - 1) / TILE;
    partition_kernel<<<ntiles, 1024, 0, stream>>>(src0, dst0, src1, dst1, src2, dst2,
                                                  gcursor, pairs, NB, NA, E, total);
    bucket_fill<<<K, 512, 0, stream>>>(pairs, gcursor, off_s, off_e, colidx, M);

    // ---- layer 1: gather + MFMA layer (bf16 plane out) ----
    const int blocksB = (NB + 63) / 64;
    const int blocksA = (NA + 63) / 64;
    gather_all<<<(M + 31) / 32, 256, 0, stream>>>(plane[0], colidx, off_s, off_e,
                                                  meanB, meanA1, meanA2, NB, NA);
    layer1_kernel<<<blocksB + blocksA, 256, 0, stream>>>(
        plane[0], plane[1], meanB, meanA1, meanA2, wh, biasC, NA, NB, blocksB);

    // ---- layer 2 + head fused via composite weights (f32 out) ----
    gather_all<<<(M + 31) / 32, 256, 0, stream>>>(plane[1], colidx, off_s, off_e,
                                                  meanB, meanA1, meanA2, NB, NA);
    layer2_head_kernel<<<blocksB + blocksA, 256, 0, stream>>>(
        plane[1], meanB, meanA1, meanA2, wh, biasC, (float*)d_out, NA, NB, blocksB);
}

// Round 11
// 381.854 us; speedup vs baseline: 1.3583x; 1.0763x over previous
//
#include <hip/hip_runtime.h>
#include <hip/hip_bf16.h>

typedef __bf16 bf16_t;
typedef unsigned short u16;
typedef short short8 __attribute__((ext_vector_type(8)));
typedef float f32x4 __attribute__((ext_vector_type(4)));

#define BSHIFT 9            // 512 dst-rows per bucket
#define CAP 8192            // fixed slots per bucket (expected 6144 +- 78; 26 sigma)
#define TILE 16384          // edges per partition tile (1024 thr x 16)

__device__ inline short f2bs(float v) {
    bf16_t h = (bf16_t)v;
    return __builtin_bit_cast(short, h);
}
__device__ inline float uif(unsigned u) { return __builtin_bit_cast(float, u); }

// ---------------- prep: plane convert + weights (incl. W_out-composites) + cursors ----
// wh mats (transposed [n*64+k], bf16):
//   0..5  Wn[l*3+e]   6,7 WrB[l]   8,9 WrA[l]=Wr[l,1]+Wr[l,2]   10 W_out
//   11 Wn[1,0]@Wout  12 Wr[1,0]@Wout  13 Wn[1,1]@Wout  14 Wn[1,2]@Wout  15 WrA[1]@Wout
// biasC f32[4][64]: 0=b[0,0]; 1=b[0,1]+b[0,2]; 2=b[1,0]@Wout+b_out; 3=(b[1,1]+b[1,2])@Wout+b_out
// Composite blocks stage both mats in LDS (round-9's scalar-global version was a
// 130us latency chain on 5 CUs).
__global__ __launch_bounds__(256) void prep_convert(
    const float* __restrict__ xA, const float* __restrict__ xB,
    const float* __restrict__ Wn, const float* __restrict__ Wr,
    const float* __restrict__ Wout, const float* __restrict__ b,
    const float* __restrict__ b_out,
    u16* __restrict__ plane0, u16* __restrict__ wh,
    int* __restrict__ gcursor, float* __restrict__ biasC,
    int NA, int NB, int K) {
    int nA4 = NA * 16, nB4 = NB * 16;
    int bA = (nA4 + 255) / 256, bB = (nB4 + 255) / 256;
    int bi = blockIdx.x;
    int tid = threadIdx.x;
    if (bi < bA + bB) {
        const float* in = (bi < bA) ? xA : xB;
        u16* out = (bi < bA) ? plane0 : plane0 + (size_t)NA * 64;
        int i = (bi < bA ? bi : bi - bA) * 256 + tid;
        int n4 = (bi < bA) ? nA4 : nB4;
        if (i >= n4) return;
        float4 v = ((const float4*)in)[i];
        u16 o[4];
        o[0] = (u16)f2bs(v.x); o[1] = (u16)f2bs(v.y);
        o[2] = (u16)f2bs(v.z); o[3] = (u16)f2bs(v.w);
        *(uint2*)(out + (size_t)i * 4) = *(uint2*)o;
        return;
    }
    if (bi < bA + bB + 11) {
        int mat = bi - bA - bB;      // 0..10
        u16* dstp = wh + (size_t)mat * 4096;
        for (int i = tid; i < 4096; i += 256) {
            int k = i >> 6, n = i & 63;
            float v;
            if (mat < 6) v = Wn[(size_t)mat * 4096 + i];
            else if (mat < 8) v = Wr[(size_t)((mat - 6) * 3 + 0) * 4096 + i];
            else if (mat < 10) v = Wr[(size_t)((mat - 8) * 3 + 1) * 4096 + i]
                                 + Wr[(size_t)((mat - 8) * 3 + 2) * 4096 + i];
            else v = Wout[i];
            dstp[n * 64 + k] = (u16)f2bs(v);
        }
        return;
    }
    if (bi < bA + bB + 11 + 5) {
        int c = bi - bA - bB - 11;   // 0..4
        const float* Wsrc;
        const float* Wsrc2 = nullptr;
        if (c == 0) Wsrc = Wn + (size_t)3 * 4096;        // Wn[1,0]
        else if (c == 1) Wsrc = Wr + (size_t)3 * 4096;   // Wr[1,0]
        else if (c == 2) Wsrc = Wn + (size_t)4 * 4096;   // Wn[1,1]
        else if (c == 3) Wsrc = Wn + (size_t)5 * 4096;   // Wn[1,2]
        else { Wsrc = Wr + (size_t)4 * 4096; Wsrc2 = Wr + (size_t)5 * 4096; }
        __shared__ float Ws[64 * 64];
        __shared__ float Wo[64 * 64];
        for (int i = tid; i < 4096; i += 256) {
            float w = Wsrc[i];
            if (Wsrc2) w += Wsrc2[i];
            Ws[i] = w;
            Wo[i] = Wout[i];
        }
        __syncthreads();
        u16* dstp = wh + (size_t)(11 + c) * 4096;
        for (int it = 0; it < 16; ++it) {
            int i = it * 256 + tid;
            int k = i >> 6, n = i & 63;
            float s0 = 0.f, s1 = 0.f, s2 = 0.f, s3 = 0.f;
#pragma unroll
            for (int j = 0; j < 64; j += 4) {
                s0 += Ws[k * 64 + j]     * Wo[j * 64 + n];
                s1 += Ws[k * 64 + j + 1] * Wo[(j + 1) * 64 + n];
                s2 += Ws[k * 64 + j + 2] * Wo[(j + 2) * 64 + n];
                s3 += Ws[k * 64 + j + 3] * Wo[(j + 3) * 64 + n];
            }
            dstp[n * 64 + k] = (u16)f2bs((s0 + s1) + (s2 + s3));
        }
        return;
    }
    // last block: cursor init + bias precompute
    for (int i = tid; i < K; i += 256) gcursor[i] = i * CAP;
    if (tid < 64) {
        int n = tid;
        float s0 = b_out[n], s1 = b_out[n];
        for (int j = 0; j < 64; j++) {
            float wo = Wout[j * 64 + n];
            s0 += b[3 * 64 + j] * wo;                       // b[1,0]
            s1 += (b[4 * 64 + j] + b[5 * 64 + j]) * wo;     // b[1,1]+b[1,2]
        }
        biasC[0 * 64 + n] = b[0 * 64 + n];
        biasC[1 * 64 + n] = b[1 * 64 + n] + b[2 * 64 + n];
        biasC[2 * 64 + n] = s0;
        biasC[3 * 64 + n] = s1;
    }
}

// pairs entry: packed = ((g & 511) << 17) | src. Scan-free tile partition;
// per-tile per-bucket run owned by ONE block (no cross-XCD line ping-pong).
__global__ __launch_bounds__(1024) void partition_kernel(
    const int* __restrict__ s0, const int* __restrict__ d0,
    const int* __restrict__ s1, const int* __restrict__ d1,
    const int* __restrict__ s2, const int* __restrict__ d2,
    int* __restrict__ gcursor, int* __restrict__ pairs,
    int NB, int NA, int E, int total) {
    __shared__ int hist[1024];
    __shared__ int gbase[1024];
    int tid = threadIdx.x;
    for (int tile = blockIdx.x * TILE; tile < total; tile += gridDim.x * TILE) {
        hist[tid] = 0;
        __syncthreads();
        int mybkt[16], mypk[16], myrank[16];
#pragma unroll
        for (int j = 0; j < 16; j++) {
            int idx = tile + j * 1024 + tid;
            int g = -1, s = 0;
            if (idx < total) {
                if (idx < E) { s = s0[idx]; g = d0[idx]; }
                else if (idx < 2 * E) { s = s1[idx - E]; g = NB + d1[idx - E]; }
                else { s = s2[idx - 2 * E]; g = NB + NA + d2[idx - 2 * E]; }
            }
            if (g >= 0) {
                mybkt[j] = g >> BSHIFT;
                mypk[j] = ((g & ((1 << BSHIFT) - 1)) << 17) | s;
                myrank[j] = atomicAdd(&hist[mybkt[j]], 1);
            } else mybkt[j] = -1;
        }
        __syncthreads();
        {
            int c = hist[tid];
            if (c) gbase[tid] = atomicAdd(&gcursor[tid], c);
        }
        __syncthreads();
#pragma unroll
        for (int j = 0; j < 16; j++) {
            if (mybkt[j] >= 0)
                pairs[gbase[mybkt[j]] + myrank[j]] = mypk[j];
        }
        __syncthreads();
    }
}

// bucket b: order pairs into colidx segments; emit per-row [off_s, off_e).
__global__ __launch_bounds__(512) void bucket_fill(const int* __restrict__ pairs,
                                                   const int* __restrict__ gcursor,
                                                   int* __restrict__ off_s,
                                                   int* __restrict__ off_e,
                                                   int* __restrict__ colidx, int M) {
    int b = blockIdx.x;
    int gb = b << BSHIFT;
    __shared__ int cnt[512], cur[512], wsum[8];
    int tid = threadIdx.x;
    int lane = tid & 63, w = tid >> 6;
    int p0 = b * CAP, p1 = gcursor[b];
    cnt[tid] = 0;
    __syncthreads();
    for (int e = p0 + tid; e < p1; e += 512)
        atomicAdd(&cnt[(unsigned)pairs[e] >> 17], 1);
    __syncthreads();
    int v = cnt[tid];
    int x = v;
#pragma unroll
    for (int off = 1; off < 64; off <<= 1) {
        int n = __shfl_up(x, off);
        if (lane >= off) x += n;
    }
    if (lane == 63) wsum[w] = x;
    __syncthreads();
    if (tid == 0) {
        int s = 0;
#pragma unroll
        for (int i = 0; i < 8; i++) { int t = wsum[i]; wsum[i] = s; s += t; }
    }
    __syncthreads();
    int excl = x - v + wsum[w];
    cur[tid] = excl;
    int g = gb + tid;
    if (g < M) { off_s[g] = p0 + excl; off_e[g] = p0 + excl + v; }
    __syncthreads();
    for (int e = p0 + tid; e < p1; e += 512) {
        int p = pairs[e];
        int pos = atomicAdd(&cur[(unsigned)p >> 17], 1);
        colidx[p0 + pos] = p & 0x1FFFF;
    }
}

// ---------------- gather one segment -> packed bf16 x8 (per lane, 1/8 row) ----------
// Same quad-pipelined loop as the proven standalone gather (59us, L2-miss-BW bound).
__device__ __forceinline__ void acc8(uint4 u, f32x4& a0, f32x4& a1) {
    a0[0] += uif(u.x << 16); a0[1] += uif(u.x & 0xFFFF0000u);
    a0[2] += uif(u.y << 16); a0[3] += uif(u.y & 0xFFFF0000u);
    a1[0] += uif(u.z << 16); a1[1] += uif(u.z & 0xFFFF0000u);
    a1[2] += uif(u.w << 16); a1[3] += uif(u.w & 0xFFFF0000u);
}

__device__ __forceinline__ uint4 gather_seg(const char* __restrict__ tab,
                                            const int* __restrict__ colidx,
                                            int s0, int s1, unsigned fo) {
    f32x4 a0 = {0.f, 0.f, 0.f, 0.f}, a1 = {0.f, 0.f, 0.f, 0.f};
    int e = s0;
    if (e + 3 < s1) {
        int c0 = colidx[e], c1 = colidx[e + 1];
        int c2 = colidx[e + 2], c3 = colidx[e + 3];
        while (e + 7 < s1) {
            uint4 u0 = *(const uint4*)(tab + (((unsigned)c0 << 7) | fo));
            uint4 u1 = *(const uint4*)(tab + (((unsigned)c1 << 7) | fo));
            uint4 u2 = *(const uint4*)(tab + (((unsigned)c2 << 7) | fo));
            uint4 u3 = *(const uint4*)(tab + (((unsigned)c3 << 7) | fo));
            c0 = colidx[e + 4]; c1 = colidx[e + 5];
            c2 = colidx[e + 6]; c3 = colidx[e + 7];
            acc8(u0, a0, a1); acc8(u1, a0, a1);
            acc8(u2, a0, a1); acc8(u3, a0, a1);
            e += 4;
        }
        {
            uint4 u0 = *(const uint4*)(tab + (((unsigned)c0 << 7) | fo));
            uint4 u1 = *(const uint4*)(tab + (((unsigned)c1 << 7) | fo));
            uint4 u2 = *(const uint4*)(tab + (((unsigned)c2 << 7) | fo));
            uint4 u3 = *(const uint4*)(tab + (((unsigned)c3 << 7) | fo));
            acc8(u0, a0, a1); acc8(u1, a0, a1);
            acc8(u2, a0, a1); acc8(u3, a0, a1);
            e += 4;
        }
    }
    for (; e < s1; ++e) {
        int c = colidx[e];
        uint4 u = *(const uint4*)(tab + (((unsigned)c << 7) | fo));
        acc8(u, a0, a1);
    }
    float inv = 1.0f / fmaxf((float)(s1 - s0), 1.0f);
    u16 o[8];
#pragma unroll
    for (int i = 0; i < 4; i++) o[i] = (u16)f2bs(a0[i] * inv);
#pragma unroll
    for (int i = 0; i < 4; i++) o[4 + i] = (u16)f2bs(a1[i] * inv);
    return *(uint4*)o;
}

// ---------------- fused gather + layer (both layers via template) --------------------
// KEY (round-5 lesson): keep gather at its native shape -- 8 segments/wave,
// octet-per-segment, 256-thread blocks -> SAME total gather-wave count as the
// standalone gather (37.5K waves). Means live only in a [32][72] u16 LDS tile
// (144B stride -> 2-way bank aliasing, free). One barrier, then the same 4 waves
// run the MFMA (B: 2 row-tiles x 2 col-pairs; A: 1 row-tile x 4 col-quarters).
// L2=0: bf16 plane out (layer 1). L2=1: composite weights, f32+relu out (layer2+head).
template <int L2>
__global__ __launch_bounds__(256) void fused_layer(
    const u16* __restrict__ plane_in, void* __restrict__ outv,
    const int* __restrict__ colidx,
    const int* __restrict__ off_s, const int* __restrict__ off_e,
    const u16* __restrict__ wh, const float* __restrict__ biasC,
    int NA, int NB, int blocksBf) {
    __shared__ __align__(16) u16 mS[32][72];
    const int tid = threadIdx.x;
    const int w = tid >> 6, lane = tid & 63;
    const int oct = lane >> 3, fl = lane & 7;
    const unsigned fo = (unsigned)(fl << 4);
    const char* pA = (const char*)plane_in;
    const char* pB = (const char*)(plane_in + (size_t)NA * 64);
    const int r = lane & 15, q = lane >> 4;
    short8 zf;
#pragma unroll
    for (int j = 0; j < 8; j++) zf[j] = 0;

    if ((int)blockIdx.x < blocksBf) {
        // ================= B path: 32 B-rows =================
        const int row0 = blockIdx.x * 32;
        {
            int seg = w * 8 + oct;               // 0..31
            int brow = row0 + seg;
            int s0 = 0, s1 = 0;
            if (brow < NB) { s0 = off_s[brow]; s1 = off_e[brow]; }
            uint4 mv = gather_seg(pA, colidx, s0, s1, fo);
            *(uint4*)&mS[seg][fl * 8] = mv;
        }
        __syncthreads();
        const int rt = w >> 1;                   // row-tile 0/1
        const int tbase = (w & 1) * 2;           // col-pair
        const int arow = row0 + rt * 16 + r;
        const bool av = arow < NB;
        const u16* WmT = wh + (size_t)(L2 ? 11 : 0) * 4096;
        const u16* WxT = wh + (size_t)(L2 ? 12 : 6) * 4096;
        const float* bb = biasC + (size_t)(L2 ? 2 : 0) * 64;
        f32x4 acc[2];
#pragma unroll
        for (int t2 = 0; t2 < 2; t2++) {
            float bv = bb[(tbase + t2) * 16 + r];
            acc[t2][0] = bv; acc[t2][1] = bv; acc[t2][2] = bv; acc[t2][3] = bv;
        }
#pragma unroll
        for (int ks = 0; ks < 2; ks++) {
            short8 am = *(const short8*)&mS[rt * 16 + r][ks * 32 + q * 8];
            short8 ax = av ? *(const short8*)(pB + (size_t)arow * 128 + ks * 64 + q * 16) : zf;
#pragma unroll
            for (int t2 = 0; t2 < 2; t2++) {
                size_t widx = (size_t)((tbase + t2) * 16 + r) * 64 + ks * 32 + q * 8;
                acc[t2] = __builtin_amdgcn_mfma_f32_16x16x32_bf16(am, *(const short8*)(WmT + widx), acc[t2], 0, 0, 0);
                acc[t2] = __builtin_amdgcn_mfma_f32_16x16x32_bf16(ax, *(const short8*)(WxT + widx), acc[t2], 0, 0, 0);
            }
        }
#pragma unroll
        for (int t2 = 0; t2 < 2; t2++) {
            int col = (tbase + t2) * 16 + r;
#pragma unroll
            for (int rr = 0; rr < 4; rr++) {
                int row = row0 + rt * 16 + q * 4 + rr;
                if (row < NB) {
                    float v = acc[t2][rr];
                    if (L2) __builtin_nontemporal_store(fmaxf(v, 0.0f),
                                (float*)outv + (size_t)(NA + row) * 64 + col);
                    else ((u16*)outv)[(size_t)(NA + row) * 64 + col] = (u16)f2bs(v);
                }
            }
        }
    } else {
        // ================= A path: 16 A-rows (32 segments) =================
        const int row0 = ((int)blockIdx.x - blocksBf) * 16;
        {
            int seg = w * 8 + oct;               // 0..31: <16 -> meanA1, else meanA2
            int rrow = row0 + (seg & 15);
            bool m2 = seg >= 16;
            int s0 = 0, s1 = 0;
            if (rrow < NA) {
                int g = m2 ? (NB + NA + rrow) : (NB + rrow);
                s0 = off_s[g]; s1 = off_e[g];
            }
            uint4 mv = gather_seg(m2 ? pA : pB, colidx, s0, s1, fo);
            *(uint4*)&mS[seg][fl * 8] = mv;
        }
        __syncthreads();
        const int t = w;                         // col-quarter
        const int arow = row0 + r;
        const bool av = arow < NA;
        const u16* Wm1T = wh + (size_t)(L2 ? 13 : 1) * 4096;
        const u16* Wm2T = wh + (size_t)(L2 ? 14 : 2) * 4096;
        const u16* WxT  = wh + (size_t)(L2 ? 15 : 8) * 4096;
        const float* bb = biasC + (size_t)(L2 ? 3 : 1) * 64;
        f32x4 acc;
        {
            float bv = bb[t * 16 + r];
            acc[0] = bv; acc[1] = bv; acc[2] = bv; acc[3] = bv;
        }
#pragma unroll
        for (int ks = 0; ks < 2; ks++) {
            short8 am1 = *(const short8*)&mS[r][ks * 32 + q * 8];
            short8 am2 = *(const short8*)&mS[16 + r][ks * 32 + q * 8];
            short8 ax = av ? *(const short8*)(pA + (size_t)arow * 128 + ks * 64 + q * 16) : zf;
            size_t widx = (size_t)(t * 16 + r) * 64 + ks * 32 + q * 8;
            acc = __builtin_amdgcn_mfma_f32_16x16x32_bf16(am1, *(const short8*)(Wm1T + widx), acc, 0, 0, 0);
            acc = __builtin_amdgcn_mfma_f32_16x16x32_bf16(am2, *(const short8*)(Wm2T + widx), acc, 0, 0, 0);
            acc = __builtin_amdgcn_mfma_f32_16x16x32_bf16(ax, *(const short8*)(WxT + widx), acc, 0, 0, 0);
        }
        {
            int col = t * 16 + r;
#pragma unroll
            for (int rr = 0; rr < 4; rr++) {
                int row = row0 + q * 4 + rr;
                if (row < NA) {
                    float v = acc[rr];
                    if (L2) __builtin_nontemporal_store(fmaxf(v, 0.0f),
                                (float*)outv + (size_t)row * 64 + col);
                    else ((u16*)outv)[(size_t)row * 64 + col] = (u16)f2bs(v);
                }
            }
        }
    }
}

// ---------------- launch ----------------
extern "C" void kernel_launch(void* const* d_in, const int* in_sizes, int n_in,
                              void* d_out, int out_size, void* d_ws, size_t ws_size,
                              hipStream_t stream) {
    const float* xA_in = (const float*)d_in[0];
    const float* xB_in = (const float*)d_in[1];
    const float* Wn = (const float*)d_in[2];
    const float* Wr = (const float*)d_in[3];
    const float* b = (const float*)d_in[4];
    const float* W_out = (const float*)d_in[5];
    const float* b_out = (const float*)d_in[6];
    const int* src0 = (const int*)d_in[7];
    const int* dst0 = (const int*)d_in[8];
    const int* src1 = (const int*)d_in[9];
    const int* dst1 = (const int*)d_in[10];
    const int* src2 = (const int*)d_in[11];
    const int* dst2 = (const int*)d_in[12];

    const int NA = in_sizes[0] / 64;
    const int NB = in_sizes[1] / 64;
    const int E = in_sizes[7];
    const int M = NB + NA + NA;
    const int total = 3 * E;
    const int K = (M + (1 << BSHIFT) - 1) >> BSHIFT;   // 586 for 300k dst rows

    // ---- workspace (means deleted; pairs standalone) ----
    const size_t PL = (size_t)(NA + NB) * 64;
    u16* plane[2];
    plane[0] = (u16*)d_ws;
    plane[1] = plane[0] + PL;
    u16* wh     = plane[1] + PL;                 // 16*4096
    int* gcursor= (int*)(wh + 16 * 4096);        // K (alloc 1024)
    float* biasC= (float*)(gcursor + 1024);      // 4*64 f32
    int* off_s  = (int*)(biasC + 256);           // M
    int* off_e  = off_s + M;                     // M
    int* colidx = off_e + M;                     // K*CAP
    int* pairs  = colidx + (size_t)K * CAP;      // K*CAP

    // ---- prep (convert + weights + composites + cursor/bias init) ----
    int bA = (NA * 16 + 255) / 256, bB = (NB * 16 + 255) / 256;
    prep_convert<<<bA + bB + 11 + 5 + 1, 256, 0, stream>>>(
        xA_in, xB_in, Wn, Wr, W_out, b, b_out,
        plane[0], wh, gcursor, biasC, NA, NB, K);

    // ---- CSR build ----
    int ntiles = (total + TILE - 1) / TILE;
    partition_kernel<<<ntiles, 1024, 0, stream>>>(src0, dst0, src1, dst1, src2, dst2,
                                                  gcursor, pairs, NB, NA, E, total);
    bucket_fill<<<K, 512, 0, stream>>>(pairs, gcursor, off_s, off_e, colidx, M);

    // ---- fused gather+layer x2 (no mean arrays, 5 dispatches total) ----
    const int blocksBf = (NB + 31) / 32;
    const int blocksAf = (NA + 15) / 16;
    fused_layer<0><<<blocksBf + blocksAf, 256, 0, stream>>>(
        plane[0], plane[1], colidx, off_s, off_e, wh, biasC, NA, NB, blocksBf);
    fused_layer<1><<<blocksBf + blocksAf, 256, 0, stream>>>(
        plane[1], d_out, colidx, off_s, off_e, wh, biasC, NA, NB, blocksBf);
}

// Round 12
// 379.193 us; speedup vs baseline: 1.3678x; 1.0070x over previous
//
#include <hip/hip_runtime.h>
#include <hip/hip_bf16.h>

typedef __bf16 bf16_t;
typedef unsigned short u16;
typedef short short8 __attribute__((ext_vector_type(8)));
typedef float f32x4 __attribute__((ext_vector_type(4)));

#define BSHIFT 9            // 512 dst-rows per bucket
#define CAP 8192            // fixed slots per bucket (expected 6144 +- 78; 26 sigma)
#define TILE 8192           // edges per partition tile (1024 thr x 8) -> 440 blocks (1.7/CU)

__device__ inline short f2bs(float v) {
    bf16_t h = (bf16_t)v;
    return __builtin_bit_cast(short, h);
}
__device__ inline float uif(unsigned u) { return __builtin_bit_cast(float, u); }

// ---------------- prep: plane convert + weights (incl. W_out-composites) + cursors ----
// wh mats (transposed [n*64+k], bf16):
//   0..5  Wn[l*3+e]   6,7 WrB[l]   8,9 WrA[l]=Wr[l,1]+Wr[l,2]   10 W_out
//   11 Wn[1,0]@Wout  12 Wr[1,0]@Wout  13 Wn[1,1]@Wout  14 Wn[1,2]@Wout  15 WrA[1]@Wout
// biasC f32[4][64]: 0=b[0,0]; 1=b[0,1]+b[0,2]; 2=b[1,0]@Wout+b_out; 3=(b[1,1]+b[1,2])@Wout+b_out
// Composite blocks stage both mats in LDS (round-9's scalar-global version was a
// 130us latency chain on 5 CUs).
__global__ __launch_bounds__(256) void prep_convert(
    const float* __restrict__ xA, const float* __restrict__ xB,
    const float* __restrict__ Wn, const float* __restrict__ Wr,
    const float* __restrict__ Wout, const float* __restrict__ b,
    const float* __restrict__ b_out,
    u16* __restrict__ plane0, u16* __restrict__ wh,
    int* __restrict__ gcursor, float* __restrict__ biasC,
    int NA, int NB, int K) {
    int nA4 = NA * 16, nB4 = NB * 16;
    int bA = (nA4 + 255) / 256, bB = (nB4 + 255) / 256;
    int bi = blockIdx.x;
    int tid = threadIdx.x;
    if (bi < bA + bB) {
        const float* in = (bi < bA) ? xA : xB;
        u16* out = (bi < bA) ? plane0 : plane0 + (size_t)NA * 64;
        int i = (bi < bA ? bi : bi - bA) * 256 + tid;
        int n4 = (bi < bA) ? nA4 : nB4;
        if (i >= n4) return;
        float4 v = ((const float4*)in)[i];
        u16 o[4];
        o[0] = (u16)f2bs(v.x); o[1] = (u16)f2bs(v.y);
        o[2] = (u16)f2bs(v.z); o[3] = (u16)f2bs(v.w);
        *(uint2*)(out + (size_t)i * 4) = *(uint2*)o;
        return;
    }
    if (bi < bA + bB + 11) {
        int mat = bi - bA - bB;      // 0..10
        u16* dstp = wh + (size_t)mat * 4096;
        for (int i = tid; i < 4096; i += 256) {
            int k = i >> 6, n = i & 63;
            float v;
            if (mat < 6) v = Wn[(size_t)mat * 4096 + i];
            else if (mat < 8) v = Wr[(size_t)((mat - 6) * 3 + 0) * 4096 + i];
            else if (mat < 10) v = Wr[(size_t)((mat - 8) * 3 + 1) * 4096 + i]
                                 + Wr[(size_t)((mat - 8) * 3 + 2) * 4096 + i];
            else v = Wout[i];
            dstp[n * 64 + k] = (u16)f2bs(v);
        }
        return;
    }
    if (bi < bA + bB + 11 + 5) {
        int c = bi - bA - bB - 11;   // 0..4
        const float* Wsrc;
        const float* Wsrc2 = nullptr;
        if (c == 0) Wsrc = Wn + (size_t)3 * 4096;        // Wn[1,0]
        else if (c == 1) Wsrc = Wr + (size_t)3 * 4096;   // Wr[1,0]
        else if (c == 2) Wsrc = Wn + (size_t)4 * 4096;   // Wn[1,1]
        else if (c == 3) Wsrc = Wn + (size_t)5 * 4096;   // Wn[1,2]
        else { Wsrc = Wr + (size_t)4 * 4096; Wsrc2 = Wr + (size_t)5 * 4096; }
        __shared__ float Ws[64 * 64];
        __shared__ float Wo[64 * 64];
        for (int i = tid; i < 4096; i += 256) {
            float w = Wsrc[i];
            if (Wsrc2) w += Wsrc2[i];
            Ws[i] = w;
            Wo[i] = Wout[i];
        }
        __syncthreads();
        u16* dstp = wh + (size_t)(11 + c) * 4096;
        for (int it = 0; it < 16; ++it) {
            int i = it * 256 + tid;
            int k = i >> 6, n = i & 63;
            float s0 = 0.f, s1 = 0.f, s2 = 0.f, s3 = 0.f;
#pragma unroll
            for (int j = 0; j < 64; j += 4) {
                s0 += Ws[k * 64 + j]     * Wo[j * 64 + n];
                s1 += Ws[k * 64 + j + 1] * Wo[(j + 1) * 64 + n];
                s2 += Ws[k * 64 + j + 2] * Wo[(j + 2) * 64 + n];
                s3 += Ws[k * 64 + j + 3] * Wo[(j + 3) * 64 + n];
            }
            dstp[n * 64 + k] = (u16)f2bs((s0 + s1) + (s2 + s3));
        }
        return;
    }
    // last block: cursor init + bias precompute
    for (int i = tid; i < K; i += 256) gcursor[i] = i * CAP;
    if (tid < 64) {
        int n = tid;
        float s0 = b_out[n], s1 = b_out[n];
        for (int j = 0; j < 64; j++) {
            float wo = Wout[j * 64 + n];
            s0 += b[3 * 64 + j] * wo;                       // b[1,0]
            s1 += (b[4 * 64 + j] + b[5 * 64 + j]) * wo;     // b[1,1]+b[1,2]
        }
        biasC[0 * 64 + n] = b[0 * 64 + n];
        biasC[1 * 64 + n] = b[1 * 64 + n] + b[2 * 64 + n];
        biasC[2 * 64 + n] = s0;
        biasC[3 * 64 + n] = s1;
    }
}

// pairs entry: packed = ((g & 511) << 17) | src. Scan-free tile partition;
// per-tile per-bucket run owned by ONE block (no cross-XCD line ping-pong).
// TILE=8192 -> 440 blocks (~1.7/CU): latency hiding beats the ~4MB extra
// write-inflation from shorter runs (round-11's 220 blocks were sub-1/CU).
__global__ __launch_bounds__(1024) void partition_kernel(
    const int* __restrict__ s0, const int* __restrict__ d0,
    const int* __restrict__ s1, const int* __restrict__ d1,
    const int* __restrict__ s2, const int* __restrict__ d2,
    int* __restrict__ gcursor, int* __restrict__ pairs,
    int NB, int NA, int E, int total) {
    __shared__ int hist[1024];
    __shared__ int gbase[1024];
    int tid = threadIdx.x;
    for (int tile = blockIdx.x * TILE; tile < total; tile += gridDim.x * TILE) {
        hist[tid] = 0;
        __syncthreads();
        int mybkt[8], mypk[8], myrank[8];
#pragma unroll
        for (int j = 0; j < 8; j++) {
            int idx = tile + j * 1024 + tid;
            int g = -1, s = 0;
            if (idx < total) {
                if (idx < E) { s = s0[idx]; g = d0[idx]; }
                else if (idx < 2 * E) { s = s1[idx - E]; g = NB + d1[idx - E]; }
                else { s = s2[idx - 2 * E]; g = NB + NA + d2[idx - 2 * E]; }
            }
            if (g >= 0) {
                mybkt[j] = g >> BSHIFT;
                mypk[j] = ((g & ((1 << BSHIFT) - 1)) << 17) | s;
                myrank[j] = atomicAdd(&hist[mybkt[j]], 1);
            } else mybkt[j] = -1;
        }
        __syncthreads();
        {
            int c = hist[tid];
            if (c) gbase[tid] = atomicAdd(&gcursor[tid], c);
        }
        __syncthreads();
#pragma unroll
        for (int j = 0; j < 8; j++) {
            if (mybkt[j] >= 0)
                pairs[gbase[mybkt[j]] + myrank[j]] = mypk[j];
        }
        __syncthreads();
    }
}

// bucket b: order pairs into colidx segments; emit per-row [off_s, off_e).
__global__ __launch_bounds__(512) void bucket_fill(const int* __restrict__ pairs,
                                                   const int* __restrict__ gcursor,
                                                   int* __restrict__ off_s,
                                                   int* __restrict__ off_e,
                                                   int* __restrict__ colidx, int M) {
    int b = blockIdx.x;
    int gb = b << BSHIFT;
    __shared__ int cnt[512], cur[512], wsum[8];
    int tid = threadIdx.x;
    int lane = tid & 63, w = tid >> 6;
    int p0 = b * CAP, p1 = gcursor[b];
    cnt[tid] = 0;
    __syncthreads();
    for (int e = p0 + tid; e < p1; e += 512)
        atomicAdd(&cnt[(unsigned)pairs[e] >> 17], 1);
    __syncthreads();
    int v = cnt[tid];
    int x = v;
#pragma unroll
    for (int off = 1; off < 64; off <<= 1) {
        int n = __shfl_up(x, off);
        if (lane >= off) x += n;
    }
    if (lane == 63) wsum[w] = x;
    __syncthreads();
    if (tid == 0) {
        int s = 0;
#pragma unroll
        for (int i = 0; i < 8; i++) { int t = wsum[i]; wsum[i] = s; s += t; }
    }
    __syncthreads();
    int excl = x - v + wsum[w];
    cur[tid] = excl;
    int g = gb + tid;
    if (g < M) { off_s[g] = p0 + excl; off_e[g] = p0 + excl + v; }
    __syncthreads();
    for (int e = p0 + tid; e < p1; e += 512) {
        int p = pairs[e];
        int pos = atomicAdd(&cur[(unsigned)p >> 17], 1);
        colidx[p0 + pos] = p & 0x1FFFF;
    }
}

// ---------------- gather one segment -> packed bf16 x8 (per lane, 1/8 row) ----------
// Same quad-pipelined loop as the proven standalone gather (59us, L2-miss-BW bound).
__device__ __forceinline__ void acc8(uint4 u, f32x4& a0, f32x4& a1) {
    a0[0] += uif(u.x << 16); a0[1] += uif(u.x & 0xFFFF0000u);
    a0[2] += uif(u.y << 16); a0[3] += uif(u.y & 0xFFFF0000u);
    a1[0] += uif(u.z << 16); a1[1] += uif(u.z & 0xFFFF0000u);
    a1[2] += uif(u.w << 16); a1[3] += uif(u.w & 0xFFFF0000u);
}

__device__ __forceinline__ uint4 gather_seg(const char* __restrict__ tab,
                                            const int* __restrict__ colidx,
                                            int s0, int s1, unsigned fo) {
    f32x4 a0 = {0.f, 0.f, 0.f, 0.f}, a1 = {0.f, 0.f, 0.f, 0.f};
    int e = s0;
    if (e + 3 < s1) {
        int c0 = colidx[e], c1 = colidx[e + 1];
        int c2 = colidx[e + 2], c3 = colidx[e + 3];
        while (e + 7 < s1) {
            uint4 u0 = *(const uint4*)(tab + (((unsigned)c0 << 7) | fo));
            uint4 u1 = *(const uint4*)(tab + (((unsigned)c1 << 7) | fo));
            uint4 u2 = *(const uint4*)(tab + (((unsigned)c2 << 7) | fo));
            uint4 u3 = *(const uint4*)(tab + (((unsigned)c3 << 7) | fo));
            c0 = colidx[e + 4]; c1 = colidx[e + 5];
            c2 = colidx[e + 6]; c3 = colidx[e + 7];
            acc8(u0, a0, a1); acc8(u1, a0, a1);
            acc8(u2, a0, a1); acc8(u3, a0, a1);
            e += 4;
        }
        {
            uint4 u0 = *(const uint4*)(tab + (((unsigned)c0 << 7) | fo));
            uint4 u1 = *(const uint4*)(tab + (((unsigned)c1 << 7) | fo));
            uint4 u2 = *(const uint4*)(tab + (((unsigned)c2 << 7) | fo));
            uint4 u3 = *(const uint4*)(tab + (((unsigned)c3 << 7) | fo));
            acc8(u0, a0, a1); acc8(u1, a0, a1);
            acc8(u2, a0, a1); acc8(u3, a0, a1);
            e += 4;
        }
    }
    for (; e < s1; ++e) {
        int c = colidx[e];
        uint4 u = *(const uint4*)(tab + (((unsigned)c << 7) | fo));
        acc8(u, a0, a1);
    }
    float inv = 1.0f / fmaxf((float)(s1 - s0), 1.0f);
    u16 o[8];
#pragma unroll
    for (int i = 0; i < 4; i++) o[i] = (u16)f2bs(a0[i] * inv);
#pragma unroll
    for (int i = 0; i < 4; i++) o[4 + i] = (u16)f2bs(a1[i] * inv);
    return *(uint4*)o;
}

// ---------------- fused gather + layer (both layers via template) --------------------
// Gather kept at native shape: 8 segments/wave, octet-per-segment, 256-thread
// blocks (same 37.5K gather waves as standalone -- round-5 lesson). Means live in
// a [32][72] u16 LDS tile. x-row fragments are HOISTED above the gather so their
// latency hides under the gather's load storm (post-barrier MFMA has no cold loads).
// L2=0: bf16 plane out (layer 1). L2=1: composite weights, f32+relu out (layer2+head).
template <int L2>
__global__ __launch_bounds__(256) void fused_layer(
    const u16* __restrict__ plane_in, void* __restrict__ outv,
    const int* __restrict__ colidx,
    const int* __restrict__ off_s, const int* __restrict__ off_e,
    const u16* __restrict__ wh, const float* __restrict__ biasC,
    int NA, int NB, int blocksBf) {
    __shared__ __align__(16) u16 mS[32][72];
    const int tid = threadIdx.x;
    const int w = tid >> 6, lane = tid & 63;
    const int oct = lane >> 3, fl = lane & 7;
    const unsigned fo = (unsigned)(fl << 4);
    const char* pA = (const char*)plane_in;
    const char* pB = (const char*)(plane_in + (size_t)NA * 64);
    const int r = lane & 15, q = lane >> 4;
    short8 zf;
#pragma unroll
    for (int j = 0; j < 8; j++) zf[j] = 0;

    if ((int)blockIdx.x < blocksBf) {
        // ================= B path: 32 B-rows =================
        const int row0 = blockIdx.x * 32;
        const int rt = w >> 1;                   // row-tile 0/1
        const int tbase = (w & 1) * 2;           // col-pair
        const int arow = row0 + rt * 16 + r;
        const bool av = arow < NB;
        // hoisted x-fragments: issue before the gather, consume after the barrier
        short8 ax0 = av ? *(const short8*)(pB + (size_t)arow * 128 + q * 16) : zf;
        short8 ax1 = av ? *(const short8*)(pB + (size_t)arow * 128 + 64 + q * 16) : zf;
        {
            int seg = w * 8 + oct;               // 0..31
            int brow = row0 + seg;
            int s0 = 0, s1 = 0;
            if (brow < NB) { s0 = off_s[brow]; s1 = off_e[brow]; }
            uint4 mv = gather_seg(pA, colidx, s0, s1, fo);
            *(uint4*)&mS[seg][fl * 8] = mv;
        }
        __syncthreads();
        const u16* WmT = wh + (size_t)(L2 ? 11 : 0) * 4096;
        const u16* WxT = wh + (size_t)(L2 ? 12 : 6) * 4096;
        const float* bb = biasC + (size_t)(L2 ? 2 : 0) * 64;
        f32x4 acc[2];
#pragma unroll
        for (int t2 = 0; t2 < 2; t2++) {
            float bv = bb[(tbase + t2) * 16 + r];
            acc[t2][0] = bv; acc[t2][1] = bv; acc[t2][2] = bv; acc[t2][3] = bv;
        }
#pragma unroll
        for (int ks = 0; ks < 2; ks++) {
            short8 am = *(const short8*)&mS[rt * 16 + r][ks * 32 + q * 8];
            short8 ax = ks ? ax1 : ax0;
#pragma unroll
            for (int t2 = 0; t2 < 2; t2++) {
                size_t widx = (size_t)((tbase + t2) * 16 + r) * 64 + ks * 32 + q * 8;
                acc[t2] = __builtin_amdgcn_mfma_f32_16x16x32_bf16(am, *(const short8*)(WmT + widx), acc[t2], 0, 0, 0);
                acc[t2] = __builtin_amdgcn_mfma_f32_16x16x32_bf16(ax, *(const short8*)(WxT + widx), acc[t2], 0, 0, 0);
            }
        }
#pragma unroll
        for (int t2 = 0; t2 < 2; t2++) {
            int col = (tbase + t2) * 16 + r;
#pragma unroll
            for (int rr = 0; rr < 4; rr++) {
                int row = row0 + rt * 16 + q * 4 + rr;
                if (row < NB) {
                    float v = acc[t2][rr];
                    if (L2) __builtin_nontemporal_store(fmaxf(v, 0.0f),
                                (float*)outv + (size_t)(NA + row) * 64 + col);
                    else ((u16*)outv)[(size_t)(NA + row) * 64 + col] = (u16)f2bs(v);
                }
            }
        }
    } else {
        // ================= A path: 16 A-rows (32 segments) =================
        const int row0 = ((int)blockIdx.x - blocksBf) * 16;
        const int t = w;                         // col-quarter
        const int arow = row0 + r;
        const bool av = arow < NA;
        // hoisted x-fragments
        short8 ax0 = av ? *(const short8*)(pA + (size_t)arow * 128 + q * 16) : zf;
        short8 ax1 = av ? *(const short8*)(pA + (size_t)arow * 128 + 64 + q * 16) : zf;
        {
            int seg = w * 8 + oct;               // 0..31: <16 -> meanA1, else meanA2
            int rrow = row0 + (seg & 15);
            bool m2 = seg >= 16;
            int s0 = 0, s1 = 0;
            if (rrow < NA) {
                int g = m2 ? (NB + NA + rrow) : (NB + rrow);
                s0 = off_s[g]; s1 = off_e[g];
            }
            uint4 mv = gather_seg(m2 ? pA : pB, colidx, s0, s1, fo);
            *(uint4*)&mS[seg][fl * 8] = mv;
        }
        __syncthreads();
        const u16* Wm1T = wh + (size_t)(L2 ? 13 : 1) * 4096;
        const u16* Wm2T = wh + (size_t)(L2 ? 14 : 2) * 4096;
        const u16* WxT  = wh + (size_t)(L2 ? 15 : 8) * 4096;
        const float* bb = biasC + (size_t)(L2 ? 3 : 1) * 64;
        f32x4 acc;
        {
            float bv = bb[t * 16 + r];
            acc[0] = bv; acc[1] = bv; acc[2] = bv; acc[3] = bv;
        }
#pragma unroll
        for (int ks = 0; ks < 2; ks++) {
            short8 am1 = *(const short8*)&mS[r][ks * 32 + q * 8];
            short8 am2 = *(const short8*)&mS[16 + r][ks * 32 + q * 8];
            short8 ax = ks ? ax1 : ax0;
            size_t widx = (size_t)(t * 16 + r) * 64 + ks * 32 + q * 8;
            acc = __builtin_amdgcn_mfma_f32_16x16x32_bf16(am1, *(const short8*)(Wm1T + widx), acc, 0, 0, 0);
            acc = __builtin_amdgcn_mfma_f32_16x16x32_bf16(am2, *(const short8*)(Wm2T + widx), acc, 0, 0, 0);
            acc = __builtin_amdgcn_mfma_f32_16x16x32_bf16(ax, *(const short8*)(WxT + widx), acc, 0, 0, 0);
        }
        {
            int col = t * 16 + r;
#pragma unroll
            for (int rr = 0; rr < 4; rr++) {
                int row = row0 + q * 4 + rr;
                if (row < NA) {
                    float v = acc[rr];
                    if (L2) __builtin_nontemporal_store(fmaxf(v, 0.0f),
                                (float*)outv + (size_t)row * 64 + col);
                    else ((u16*)outv)[(size_t)row * 64 + col] = (u16)f2bs(v);
                }
            }
        }
    }
}

// ---------------- launch ----------------
extern "C" void kernel_launch(void* const* d_in, const int* in_sizes, int n_in,
                              void* d_out, int out_size, void* d_ws, size_t ws_size,
                              hipStream_t stream) {
    const float* xA_in = (const float*)d_in[0];
    const float* xB_in = (const float*)d_in[1];
    const float* Wn = (const float*)d_in[2];
    const float* Wr = (const float*)d_in[3];
    const float* b = (const float*)d_in[4];
    const float* W_out = (const float*)d_in[5];
    const float* b_out = (const float*)d_in[6];
    const int* src0 = (const int*)d_in[7];
    const int* dst0 = (const int*)d_in[8];
    const int* src1 = (const int*)d_in[9];
    const int* dst1 = (const int*)d_in[10];
    const int* src2 = (const int*)d_in[11];
    const int* dst2 = (const int*)d_in[12];

    const int NA = in_sizes[0] / 64;
    const int NB = in_sizes[1] / 64;
    const int E = in_sizes[7];
    const int M = NB + NA + NA;
    const int total = 3 * E;
    const int K = (M + (1 << BSHIFT) - 1) >> BSHIFT;   // 586 for 300k dst rows

    // ---- workspace (means deleted; pairs standalone) ----
    const size_t PL = (size_t)(NA + NB) * 64;
    u16* plane[2];
    plane[0] = (u16*)d_ws;
    plane[1] = plane[0] + PL;
    u16* wh     = plane[1] + PL;                 // 16*4096
    int* gcursor= (int*)(wh + 16 * 4096);        // K (alloc 1024)
    float* biasC= (float*)(gcursor + 1024);      // 4*64 f32
    int* off_s  = (int*)(biasC + 256);           // M
    int* off_e  = off_s + M;                     // M
    int* colidx = off_e + M;                     // K*CAP
    int* pairs  = colidx + (size_t)K * CAP;      // K*CAP

    // ---- prep (convert + weights + composites + cursor/bias init) ----
    int bA = (NA * 16 + 255) / 256, bB = (NB * 16 + 255) / 256;
    prep_convert<<<bA + bB + 11 + 5 + 1, 256, 0, stream>>>(
        xA_in, xB_in, Wn, Wr, W_out, b, b_out,
        plane[0], wh, gcursor, biasC, NA, NB, K);

    // ---- CSR build ----
    int ntiles = (total + TILE - 1) / TILE;
    partition_kernel<<<ntiles, 1024, 0, stream>>>(src0, dst0, src1, dst1, src2, dst2,
                                                  gcursor, pairs, NB, NA, E, total);
    bucket_fill<<<K, 512, 0, stream>>>(pairs, gcursor, off_s, off_e, colidx, M);

    // ---- fused gather+layer x2 (no mean arrays, 5 dispatches total) ----
    const int blocksBf = (NB + 31) / 32;
    const int blocksAf = (NA + 15) / 16;
    fused_layer<0><<<blocksBf + blocksAf, 256, 0, stream>>>(
        plane[0], plane[1], colidx, off_s, off_e, wh, biasC, NA, NB, blocksBf);
    fused_layer<1><<<blocksBf + blocksAf, 256, 0, stream>>>(
        plane[1], d_out, colidx, off_s, off_e, wh, biasC, NA, NB, blocksBf);
}